// Round 1
// baseline (933.529 us; speedup 1.0000x reference)
//
#include <hip/hip_runtime.h>

#define NNODES 100000
#define NEDGES 1600000
#define D 64
#define EPSN 1e-12f

// ---------------------------------------------------------------------------
// Scatter: agg[dst[e]][lane] += feat[src[e]][lane], one lane per (edge,feat).
// ---------------------------------------------------------------------------
__global__ void scatter_add_kernel(const float* __restrict__ feat,
                                   const int* __restrict__ src,
                                   const int* __restrict__ dst,
                                   float* __restrict__ agg) {
    unsigned long long idx =
        (unsigned long long)blockIdx.x * blockDim.x + threadIdx.x;
    unsigned e = (unsigned)(idx >> 6);
    unsigned lane = (unsigned)(idx & 63);
    if (e >= NEDGES) return;
    int s = src[e];
    int d = dst[e];
    float v = feat[(size_t)s * D + lane];
    unsafeAtomicAdd(&agg[(size_t)d * D + lane], v);   // global_atomic_add_f32
}

// ---------------------------------------------------------------------------
// Node transform: out[n][o] = sum_k agg[n][k]*Wl[o][k] + bl[o]
//                           + sum_k  xin[n][k]*Wr[o][k]
// RELU_NORM: relu then row-L2-normalize (layer 1); else plain (layer 2).
// 256 threads: 4 nodes per group, thread (nl, o) computes one output element.
// ---------------------------------------------------------------------------
template <bool RELU_NORM>
__global__ void node_kernel(const float* __restrict__ agg,
                            const float* __restrict__ xin,
                            const float* __restrict__ Wl,
                            const float* __restrict__ bl,
                            const float* __restrict__ Wr,
                            float* __restrict__ out) {
    __shared__ float WlT[D * D];   // WlT[k*D+o] = Wl[o*D+k]
    __shared__ float WrT[D * D];
    __shared__ float blv[D];
    __shared__ float rows[4][2][D];  // [node-in-group][agg|x][k]

    const int tid = threadIdx.x;
    for (int i = tid; i < D * D; i += blockDim.x) {
        int o = i / D, k = i % D;
        WlT[k * D + o] = Wl[i];
        WrT[k * D + o] = Wr[i];
    }
    if (tid < D) blv[tid] = bl[tid];
    __syncthreads();

    const int nl = tid >> 6;   // node within group (0..3)
    const int o  = tid & 63;   // output feature

    const int ngroups = (NNODES + 3) / 4;
    for (int g = blockIdx.x; g < ngroups; g += gridDim.x) {
        int node = g * 4 + nl;
        // stage input rows (each thread loads 2 floats)
        if (node < NNODES) {
            rows[nl][0][o] = agg[(size_t)node * D + o];
            rows[nl][1][o] = xin[(size_t)node * D + o];
        }
        __syncthreads();

        if (node < NNODES) {
            float acc = blv[o];
            #pragma unroll
            for (int k = 0; k < D; ++k) {
                acc += rows[nl][0][k] * WlT[k * D + o];
                acc += rows[nl][1][k] * WrT[k * D + o];
            }
            if (RELU_NORM) {
                acc = fmaxf(acc, 0.0f);
                float ss = acc * acc;
                #pragma unroll
                for (int m = 32; m >= 1; m >>= 1)
                    ss += __shfl_xor(ss, m, 64);
                float nrm = sqrtf(ss);
                acc = acc / fmaxf(nrm, EPSN);
            }
            out[(size_t)node * D + o] = acc;
        }
        __syncthreads();
    }
}

extern "C" void kernel_launch(void* const* d_in, const int* in_sizes, int n_in,
                              void* d_out, int out_size, void* d_ws, size_t ws_size,
                              hipStream_t stream) {
    const float* x   = (const float*)d_in[0];
    const int* eidx  = (const int*)d_in[1];
    // d_in[2] = edge_feature (unused)
    const float* W1l = (const float*)d_in[3];
    const float* b1l = (const float*)d_in[4];
    const float* W1r = (const float*)d_in[5];
    const float* W2l = (const float*)d_in[6];
    const float* b2l = (const float*)d_in[7];
    const float* W2r = (const float*)d_in[8];
    float* out = (float*)d_out;

    const int* src = eidx;            // edge_index[0]
    const int* dst = eidx + NEDGES;   // edge_index[1]

    float* agg = (float*)d_ws;                       // [N, D]
    float* h   = agg + (size_t)NNODES * D;           // [N, D]

    const size_t nd_bytes = (size_t)NNODES * D * sizeof(float);

    dim3 blk(256);
    dim3 scat_grid((unsigned)(((unsigned long long)NEDGES * 64 + 255) / 256));
    dim3 node_grid(2048);

    // ---- layer 1 ----
    hipMemsetAsync(agg, 0, nd_bytes, stream);
    scatter_add_kernel<<<scat_grid, blk, 0, stream>>>(x, src, dst, agg);
    node_kernel<true><<<node_grid, blk, 0, stream>>>(agg, x, W1l, b1l, W1r, h);

    // ---- layer 2 ----
    hipMemsetAsync(agg, 0, nd_bytes, stream);
    scatter_add_kernel<<<scat_grid, blk, 0, stream>>>(h, src, dst, agg);
    node_kernel<false><<<node_grid, blk, 0, stream>>>(agg, h, W2l, b2l, W2r, out);
}

// Round 2
// 585.141 us; speedup vs baseline: 1.5954x; 1.5954x over previous
//
#include <hip/hip_runtime.h>

#define NNODES 100000
#define NEDGES 1600000
#define D 64
#define EPSN 1e-12f
#define NB ((NNODES + 255) / 256)   // 391 scan blocks

// ---------------------------------------------------------------------------
// CSR build: hist -> scan (3 kernels) -> place
// ---------------------------------------------------------------------------
__global__ void hist_kernel(const int* __restrict__ dst, int* __restrict__ deg) {
    int e = blockIdx.x * 256 + threadIdx.x;
    if (e < NEDGES) atomicAdd(&deg[dst[e]], 1);
}

__global__ void scan1_kernel(const int* __restrict__ deg,
                             int* __restrict__ rowptr,
                             int* __restrict__ blocksums) {
    __shared__ int s[256];
    const int t = threadIdx.x;
    const int i = blockIdx.x * 256 + t;
    const int v = (i < NNODES) ? deg[i] : 0;
    int val = v;
    s[t] = val;
    __syncthreads();
    for (int off = 1; off < 256; off <<= 1) {
        int add = (t >= off) ? s[t - off] : 0;
        __syncthreads();
        val += add;
        s[t] = val;
        __syncthreads();
    }
    if (i < NNODES) rowptr[i] = val - v;       // block-local exclusive
    if (t == 255) blocksums[blockIdx.x] = val; // block total
}

__global__ void scan2_kernel(const int* __restrict__ blocksums,
                             int* __restrict__ blockoff) {
    __shared__ int s[512];
    const int t = threadIdx.x;
    const int v = (t < NB) ? blocksums[t] : 0;
    int val = v;
    s[t] = val;
    __syncthreads();
    for (int off = 1; off < 512; off <<= 1) {
        int add = (t >= off) ? s[t - off] : 0;
        __syncthreads();
        val += add;
        s[t] = val;
        __syncthreads();
    }
    if (t < NB) blockoff[t] = val - v;         // exclusive
}

__global__ void scan3_kernel(int* __restrict__ rowptr,
                             const int* __restrict__ blockoff) {
    const int i = blockIdx.x * 256 + threadIdx.x;
    if (i < NNODES) rowptr[i] += blockoff[blockIdx.x];
    if (i == 0) rowptr[NNODES] = NEDGES;
}

__global__ void place_kernel(const int* __restrict__ src,
                             const int* __restrict__ dst,
                             const int* __restrict__ rowptr,
                             int* __restrict__ cursor,
                             int* __restrict__ ssrc) {
    const int e = blockIdx.x * 256 + threadIdx.x;
    if (e >= NEDGES) return;
    const int d = dst[e];
    const int p = rowptr[d] + atomicAdd(&cursor[d], 1);
    ssrc[p] = src[e];
}

// ---------------------------------------------------------------------------
// Fused SAGE layer: per-node wave gathers+sums neighbor rows (float4, 4
// edges/iter), then applies out = agg@Wl^T + bl + x@Wr^T with weight columns
// held in per-lane registers. RELU_NORM adds relu + row L2-normalize.
// ---------------------------------------------------------------------------
template <bool RELU_NORM>
__global__ __launch_bounds__(256) void sage_layer_kernel(
    const float* __restrict__ xin,
    const int* __restrict__ rowptr,
    const int* __restrict__ ssrc,
    const float* __restrict__ Wl,
    const float* __restrict__ bl,
    const float* __restrict__ Wr,
    float* __restrict__ out)
{
    __shared__ float smem[2 * D * D];  // phase 1: WlT|WrT staging; phase 2: rows
    const int tid  = threadIdx.x;
    const int w    = tid >> 6;
    const int lane = tid & 63;

    // stage transposed weights in LDS (coalesced global reads)
    for (int i = tid; i < D * D; i += 256) {
        int o = i >> 6, k = i & 63;
        smem[k * D + o]         = Wl[i];
        smem[D * D + k * D + o] = Wr[i];
    }
    __syncthreads();
    // pull this lane's weight columns into registers (conflict-free reads)
    float wl[D], wr[D];
    #pragma unroll
    for (int k = 0; k < D; ++k) {
        wl[k] = smem[k * D + lane];
        wr[k] = smem[D * D + k * D + lane];
    }
    const float bias = bl[lane];
    __syncthreads();

    float* aggrow = &smem[w * 2 * D];      // 64 floats, private to wave w
    float* xrow   = &smem[w * 2 * D + D];  // 64 floats
    const int grp = lane >> 4;   // edge subgroup 0..3
    const int fq  = lane & 15;   // feature quarter

    const int stride = gridDim.x * 4;
    for (int node = blockIdx.x * 4 + w; node < NNODES; node += stride) {
        const int beg = rowptr[node];
        const int end = rowptr[node + 1];
        float4 acc = make_float4(0.f, 0.f, 0.f, 0.f);
        for (int j0 = beg; j0 < end; j0 += 64) {
            const int nj = min(64, end - j0);
            const int s64 = (lane < nj) ? ssrc[j0 + lane] : 0;
            for (int j = 0; j < nj; j += 4) {
                const int myj = j + grp;
                const int s = __shfl(s64, myj, 64);
                if (myj < nj) {
                    const float4 v = *reinterpret_cast<const float4*>(
                        &xin[(size_t)s * D + fq * 4]);
                    acc.x += v.x; acc.y += v.y; acc.z += v.z; acc.w += v.w;
                }
            }
        }
        // combine the 4 edge subgroups (each holds full feature coverage)
        #pragma unroll
        for (int m = 16; m < 64; m <<= 1) {
            acc.x += __shfl_xor(acc.x, m, 64);
            acc.y += __shfl_xor(acc.y, m, 64);
            acc.z += __shfl_xor(acc.z, m, 64);
            acc.w += __shfl_xor(acc.w, m, 64);
        }
        if (lane < 16) *reinterpret_cast<float4*>(&aggrow[lane * 4]) = acc;
        xrow[lane] = xin[(size_t)node * D + lane];
        // same-wave LDS write->read; compiler inserts lgkmcnt
        float oacc = bias;
        #pragma unroll
        for (int k = 0; k < D; ++k) {
            oacc += aggrow[k] * wl[k] + xrow[k] * wr[k];
        }
        if (RELU_NORM) {
            oacc = fmaxf(oacc, 0.f);
            float ss = oacc * oacc;
            #pragma unroll
            for (int m = 1; m < 64; m <<= 1) ss += __shfl_xor(ss, m, 64);
            oacc = oacc / fmaxf(sqrtf(ss), EPSN);
        }
        out[(size_t)node * D + lane] = oacc;
    }
}

extern "C" void kernel_launch(void* const* d_in, const int* in_sizes, int n_in,
                              void* d_out, int out_size, void* d_ws, size_t ws_size,
                              hipStream_t stream) {
    const float* x   = (const float*)d_in[0];
    const int* eidx  = (const int*)d_in[1];
    // d_in[2] = edge_feature (unused)
    const float* W1l = (const float*)d_in[3];
    const float* b1l = (const float*)d_in[4];
    const float* W1r = (const float*)d_in[5];
    const float* W2l = (const float*)d_in[6];
    const float* b2l = (const float*)d_in[7];
    const float* W2r = (const float*)d_in[8];
    float* out = (float*)d_out;

    const int* src = eidx;            // edge_index[0]
    const int* dst = eidx + NEDGES;   // edge_index[1]

    // workspace layout (16B-aligned chunks)
    char* ws = (char*)d_ws;
    int* deg       = (int*)ws;                 ws += ((size_t)NNODES * 4 + 15) / 16 * 16;
    int* rowptr    = (int*)ws;                 ws += ((size_t)(NNODES + 1) * 4 + 15) / 16 * 16;
    int* cursor    = (int*)ws;                 ws += ((size_t)NNODES * 4 + 15) / 16 * 16;
    int* ssrc      = (int*)ws;                 ws += ((size_t)NEDGES * 4 + 15) / 16 * 16;
    int* blocksums = (int*)ws;                 ws += ((size_t)NB * 4 + 15) / 16 * 16;
    int* blockoff  = (int*)ws;                 ws += ((size_t)NB * 4 + 15) / 16 * 16;
    float* h       = (float*)ws;               // [N, D]

    dim3 blk(256);
    dim3 egrid((NEDGES + 255) / 256);
    dim3 sgrid(NB);
    dim3 lgrid(1536);

    // ---- CSR build (shared by both layers) ----
    hipMemsetAsync(deg, 0, (size_t)NNODES * 4, stream);
    hipMemsetAsync(cursor, 0, (size_t)NNODES * 4, stream);
    hist_kernel<<<egrid, blk, 0, stream>>>(dst, deg);
    scan1_kernel<<<sgrid, blk, 0, stream>>>(deg, rowptr, blocksums);
    scan2_kernel<<<1, 512, 0, stream>>>(blocksums, blockoff);
    scan3_kernel<<<sgrid, blk, 0, stream>>>(rowptr, blockoff);
    place_kernel<<<egrid, blk, 0, stream>>>(src, dst, rowptr, cursor, ssrc);

    // ---- layer 1: h = normalize(relu(agg@W1l^T + b1l + x@W1r^T)) ----
    sage_layer_kernel<true><<<lgrid, blk, 0, stream>>>(
        x, rowptr, ssrc, W1l, b1l, W1r, h);

    // ---- layer 2: out = agg(h)@W2l^T + b2l + h@W2r^T ----
    sage_layer_kernel<false><<<lgrid, blk, 0, stream>>>(
        h, rowptr, ssrc, W2l, b2l, W2r, out);
}

// Round 3
// 432.334 us; speedup vs baseline: 2.1593x; 1.3534x over previous
//
#include <hip/hip_runtime.h>

#define NNODES 100000
#define NEDGES 1600000
#define D 64
#define EPSN 1e-12f
#define NB ((NNODES + 255) / 256)   // 391 scan blocks

// ---------------------------------------------------------------------------
// CSR build: hist -> scan (3 kernels) -> place
// ---------------------------------------------------------------------------
__global__ void hist_kernel(const int* __restrict__ dst, int* __restrict__ deg) {
    int e = blockIdx.x * 256 + threadIdx.x;
    if (e < NEDGES) atomicAdd(&deg[dst[e]], 1);
}

__global__ void scan1_kernel(const int* __restrict__ deg,
                             int* __restrict__ rowptr,
                             int* __restrict__ blocksums) {
    __shared__ int s[256];
    const int t = threadIdx.x;
    const int i = blockIdx.x * 256 + t;
    const int v = (i < NNODES) ? deg[i] : 0;
    int val = v;
    s[t] = val;
    __syncthreads();
    for (int off = 1; off < 256; off <<= 1) {
        int add = (t >= off) ? s[t - off] : 0;
        __syncthreads();
        val += add;
        s[t] = val;
        __syncthreads();
    }
    if (i < NNODES) rowptr[i] = val - v;       // block-local exclusive
    if (t == 255) blocksums[blockIdx.x] = val; // block total
}

__global__ void scan2_kernel(const int* __restrict__ blocksums,
                             int* __restrict__ blockoff) {
    __shared__ int s[512];
    const int t = threadIdx.x;
    const int v = (t < NB) ? blocksums[t] : 0;
    int val = v;
    s[t] = val;
    __syncthreads();
    for (int off = 1; off < 512; off <<= 1) {
        int add = (t >= off) ? s[t - off] : 0;
        __syncthreads();
        val += add;
        s[t] = val;
        __syncthreads();
    }
    if (t < NB) blockoff[t] = val - v;         // exclusive
}

__global__ void scan3_kernel(int* __restrict__ rowptr,
                             const int* __restrict__ blockoff) {
    const int i = blockIdx.x * 256 + threadIdx.x;
    if (i < NNODES) rowptr[i] += blockoff[blockIdx.x];
    if (i == 0) rowptr[NNODES] = NEDGES;
}

__global__ void place_kernel(const int* __restrict__ src,
                             const int* __restrict__ dst,
                             const int* __restrict__ rowptr,
                             int* __restrict__ cursor,
                             int* __restrict__ ssrc) {
    const int e = blockIdx.x * 256 + threadIdx.x;
    if (e >= NEDGES) return;
    const int d = dst[e];
    const int p = rowptr[d] + atomicAdd(&cursor[d], 1);
    ssrc[p] = src[e];
}

// ---------------------------------------------------------------------------
// Gather: agg[n] = sum_{s in row(n)} feat[s].  Quarter-wave (16 lanes) per
// node, float4 per lane => one 256B coalesced request per edge-row.  No LDS,
// tiny VGPR footprint -> max occupancy, 4 gathers in flight per iteration.
// ---------------------------------------------------------------------------
__global__ __launch_bounds__(256) void gather_kernel(
    const float* __restrict__ feat,
    const int* __restrict__ rowptr,
    const int* __restrict__ ssrc,
    float* __restrict__ agg)
{
    const int tid = threadIdx.x;
    const int quarter = tid >> 4;            // 0..15
    const int f = tid & 15;                  // float4 slot within row
    const int node = blockIdx.x * 16 + quarter;
    if (node >= NNODES) return;

    const int beg = rowptr[node];
    const int end = rowptr[node + 1];
    const float* fb = feat + (size_t)f * 4;

    float ax = 0.f, ay = 0.f, az = 0.f, aw = 0.f;
    int j = beg;
    for (; j + 4 <= end; j += 4) {
        const int s0 = ssrc[j + 0];
        const int s1 = ssrc[j + 1];
        const int s2 = ssrc[j + 2];
        const int s3 = ssrc[j + 3];
        const float4 v0 = *reinterpret_cast<const float4*>(&fb[(size_t)s0 * D]);
        const float4 v1 = *reinterpret_cast<const float4*>(&fb[(size_t)s1 * D]);
        const float4 v2 = *reinterpret_cast<const float4*>(&fb[(size_t)s2 * D]);
        const float4 v3 = *reinterpret_cast<const float4*>(&fb[(size_t)s3 * D]);
        ax += v0.x + v1.x + v2.x + v3.x;
        ay += v0.y + v1.y + v2.y + v3.y;
        az += v0.z + v1.z + v2.z + v3.z;
        aw += v0.w + v1.w + v2.w + v3.w;
    }
    for (; j < end; ++j) {
        const int s = ssrc[j];
        const float4 v = *reinterpret_cast<const float4*>(&fb[(size_t)s * D]);
        ax += v.x; ay += v.y; az += v.z; aw += v.w;
    }
    float4 r; r.x = ax; r.y = ay; r.z = az; r.w = aw;
    *reinterpret_cast<float4*>(&agg[(size_t)node * D + f * 4]) = r;
}

// ---------------------------------------------------------------------------
// Transform: out[n][o] = bias[o] + sum_k agg[n][k]*Wl[o][k] + xin[n][k]*Wr[o][k]
// One wave per block; lane o holds Wl[o][:], Wr[o][:] in 128 registers
// (launch_bounds(64,2) -> 256-VGPR cap, no spill).  Rows staged in a 512B
// LDS buffer, consumed as b128 broadcasts.  RELU_NORM fuses relu + L2-norm.
// ---------------------------------------------------------------------------
template <bool RELU_NORM>
__global__ __launch_bounds__(64, 2) void transform_kernel(
    const float* __restrict__ agg,
    const float* __restrict__ xin,
    const float* __restrict__ Wl,
    const float* __restrict__ bl,
    const float* __restrict__ Wr,
    float* __restrict__ out)
{
    __shared__ float rowbuf[2][D];
    const int lane = threadIdx.x;

    float wl[D], wr[D];
    #pragma unroll
    for (int kb = 0; kb < 16; ++kb) {
        const float4 a = *reinterpret_cast<const float4*>(&Wl[lane * D + kb * 4]);
        const float4 b = *reinterpret_cast<const float4*>(&Wr[lane * D + kb * 4]);
        wl[kb * 4 + 0] = a.x; wl[kb * 4 + 1] = a.y;
        wl[kb * 4 + 2] = a.z; wl[kb * 4 + 3] = a.w;
        wr[kb * 4 + 0] = b.x; wr[kb * 4 + 1] = b.y;
        wr[kb * 4 + 2] = b.z; wr[kb * 4 + 3] = b.w;
    }
    const float bias = bl[lane];

    for (int node = blockIdx.x; node < NNODES; node += gridDim.x) {
        if (lane < 16) {
            *reinterpret_cast<float4*>(&rowbuf[0][lane * 4]) =
                *reinterpret_cast<const float4*>(&agg[(size_t)node * D + lane * 4]);
        } else if (lane < 32) {
            const int f = lane & 15;
            *reinterpret_cast<float4*>(&rowbuf[1][f * 4]) =
                *reinterpret_cast<const float4*>(&xin[(size_t)node * D + f * 4]);
        }
        __syncthreads();   // single-wave block: compiles to waitcnt + cheap barrier

        float oacc = bias;
        #pragma unroll
        for (int kb = 0; kb < 16; ++kb) {
            const float4 a  = *reinterpret_cast<const float4*>(&rowbuf[0][kb * 4]);
            const float4 xv = *reinterpret_cast<const float4*>(&rowbuf[1][kb * 4]);
            oacc += a.x  * wl[kb * 4 + 0] + a.y  * wl[kb * 4 + 1]
                  + a.z  * wl[kb * 4 + 2] + a.w  * wl[kb * 4 + 3];
            oacc += xv.x * wr[kb * 4 + 0] + xv.y * wr[kb * 4 + 1]
                  + xv.z * wr[kb * 4 + 2] + xv.w * wr[kb * 4 + 3];
        }
        if (RELU_NORM) {
            oacc = fmaxf(oacc, 0.f);
            float ss = oacc * oacc;
            #pragma unroll
            for (int m = 1; m < 64; m <<= 1) ss += __shfl_xor(ss, m, 64);
            oacc = oacc / fmaxf(sqrtf(ss), EPSN);
        }
        out[(size_t)node * D + lane] = oacc;
        __syncthreads();   // protect rowbuf before next iteration's writes
    }
}

extern "C" void kernel_launch(void* const* d_in, const int* in_sizes, int n_in,
                              void* d_out, int out_size, void* d_ws, size_t ws_size,
                              hipStream_t stream) {
    const float* x   = (const float*)d_in[0];
    const int* eidx  = (const int*)d_in[1];
    // d_in[2] = edge_feature (unused)
    const float* W1l = (const float*)d_in[3];
    const float* b1l = (const float*)d_in[4];
    const float* W1r = (const float*)d_in[5];
    const float* W2l = (const float*)d_in[6];
    const float* b2l = (const float*)d_in[7];
    const float* W2r = (const float*)d_in[8];
    float* out = (float*)d_out;

    const int* src = eidx;            // edge_index[0]
    const int* dst = eidx + NEDGES;   // edge_index[1]

    // workspace layout (16B-aligned chunks)
    char* ws = (char*)d_ws;
    int* deg       = (int*)ws;                 ws += ((size_t)NNODES * 4 + 15) / 16 * 16;
    int* rowptr    = (int*)ws;                 ws += ((size_t)(NNODES + 1) * 4 + 15) / 16 * 16;
    int* cursor    = (int*)ws;                 ws += ((size_t)NNODES * 4 + 15) / 16 * 16;
    int* ssrc      = (int*)ws;                 ws += ((size_t)NEDGES * 4 + 15) / 16 * 16;
    int* blocksums = (int*)ws;                 ws += ((size_t)NB * 4 + 15) / 16 * 16;
    int* blockoff  = (int*)ws;                 ws += ((size_t)NB * 4 + 15) / 16 * 16;
    float* agg     = (float*)ws;               // [N, D]
    float* h       = out;                      // layer-1 output lives in d_out

    dim3 blk(256);
    dim3 egrid((NEDGES + 255) / 256);
    dim3 sgrid(NB);
    dim3 ggrid((NNODES + 15) / 16);
    dim3 tgrid(4096);
    dim3 tblk(64);

    // ---- CSR build (shared by both layers) ----
    hipMemsetAsync(deg, 0, (size_t)NNODES * 4, stream);
    hipMemsetAsync(cursor, 0, (size_t)NNODES * 4, stream);
    hist_kernel<<<egrid, blk, 0, stream>>>(dst, deg);
    scan1_kernel<<<sgrid, blk, 0, stream>>>(deg, rowptr, blocksums);
    scan2_kernel<<<1, 512, 0, stream>>>(blocksums, blockoff);
    scan3_kernel<<<sgrid, blk, 0, stream>>>(rowptr, blockoff);
    place_kernel<<<egrid, blk, 0, stream>>>(src, dst, rowptr, cursor, ssrc);

    // ---- layer 1: h = normalize(relu(agg@W1l^T + b1l + x@W1r^T)) ----
    gather_kernel<<<ggrid, blk, 0, stream>>>(x, rowptr, ssrc, agg);
    transform_kernel<true><<<tgrid, tblk, 0, stream>>>(agg, x, W1l, b1l, W1r, h);

    // ---- layer 2: out = agg(h)@W2l^T + b2l + h@W2r^T ----
    gather_kernel<<<ggrid, blk, 0, stream>>>(h, rowptr, ssrc, agg);
    transform_kernel<false><<<tgrid, tblk, 0, stream>>>(agg, h, W2l, b2l, W2r, out);
}